// Round 6
// baseline (451.946 us; speedup 1.0000x reference)
//
#include <hip/hip_runtime.h>
#include <math.h>
#include <stdint.h>

using u16 = unsigned short;
using u32 = uint32_t;

// Problem constants
constexpr int cB = 2;
constexpr int cQ = 1024;
constexpr int cM = 1024;
constexpr int cU = 1024;
constexpr int cH = 16;
constexpr int cD = 64;
constexpr int cK = 2048;   // KLEN
constexpr int cWPAD = 2176; // w_all row stride (covers OOB window reads to 2111)

typedef __bf16 v8bf  __attribute__((ext_vector_type(8)));
typedef float  v16f  __attribute__((ext_vector_type(16)));

#define MFMA32(a, b, c) __builtin_amdgcn_mfma_f32_32x32x16_bf16((a), (b), (c), 0, 0, 0)

__device__ __forceinline__ u16 f2bf(float f) {   // RTN float->bf16 bits
    u32 u = __float_as_uint(f);
    u += 0x7fffu + ((u >> 16) & 1u);
    return (u16)(u >> 16);
}
__device__ __forceinline__ float bf2f(u16 s) {
    return __uint_as_float(((u32)s) << 16);
}

union Frag { v8bf v; u16 s[8]; uint2 d2[2]; uint4 q4; };

typedef const u32 __attribute__((address_space(1)))* gp1;
typedef u32 __attribute__((address_space(3)))* lp3;

// ---------------------------------------------------------------------------
// Convert activations to bf16 hi/lo planes (unchanged).
// ---------------------------------------------------------------------------
__global__ __launch_bounds__(256)
void convert_acts(const float* __restrict__ inputs, const float* __restrict__ memories,
                  const float* __restrict__ relatives,
                  u16* __restrict__ fullH, u16* __restrict__ fullL,
                  u16* __restrict__ relH,  u16* __restrict__ relL)
{
    const int idx = blockIdx.x * 256 + threadIdx.x;   // quad index
    const float* src;
    u16 *dh, *dl;
    int q;
    if (idx < (1 << 20)) {                            // full = concat(mem, inp)
        q = idx;
        const int row = q >> 8;
        const int col = (q & 255) * 4;
        const int b = row >> 11, l = row & (cK - 1);
        src = (l < cM) ? (memories + ((size_t)b * cM + l) * cU + col)
                       : (inputs   + ((size_t)b * cQ + (l - cM)) * cU + col);
        dh = fullH; dl = fullL;
    } else {
        q = idx - (1 << 20);
        src = relatives + (size_t)q * 4;
        dh = relH; dl = relL;
    }
    const float4 f = *(const float4*)src;
    const float xs[4] = {f.x, f.y, f.z, f.w};
    u16 hi[4], lo[4];
    #pragma unroll
    for (int j = 0; j < 4; ++j) {
        hi[j] = f2bf(xs[j]);
        lo[j] = f2bf(xs[j] - bf2f(hi[j]));
    }
    uint2 ph, pl;
    ph.x = hi[0] | ((u32)hi[1] << 16); ph.y = hi[2] | ((u32)hi[3] << 16);
    pl.x = lo[0] | ((u32)lo[1] << 16); pl.y = lo[2] | ((u32)lo[3] << 16);
    *(uint2*)(dh + (size_t)q * 4) = ph;
    *(uint2*)(dl + (size_t)q * 4) = pl;
}

// ---------------------------------------------------------------------------
// Convert + TRANSPOSE weights to bf16 hi/lo (unchanged).
// ---------------------------------------------------------------------------
__global__ __launch_bounds__(256)
void convert_wT(const float* __restrict__ Wq, const float* __restrict__ Wkv,
                const float* __restrict__ Wr, const float* __restrict__ Wo,
                u16* __restrict__ WqTH, u16* __restrict__ WqTL,
                u16* __restrict__ WkvTH, u16* __restrict__ WkvTL,
                u16* __restrict__ WrTH, u16* __restrict__ WrTL,
                u16* __restrict__ WoTH, u16* __restrict__ WoTL)
{
    __shared__ float tl[64][65];
    const int t = threadIdx.x;
    int bid = blockIdx.x;
    const float* src; u16 *dh, *dl; int N, tK, tN;
    if (bid < 256)       { src = Wq;  dh = WqTH;  dl = WqTL;  N = 1024; tK = bid >> 4; tN = bid & 15; }
    else if (bid < 768)  { bid -= 256; src = Wkv; dh = WkvTH; dl = WkvTL; N = 2048; tK = bid >> 5; tN = bid & 31; }
    else if (bid < 1024) { bid -= 768; src = Wr;  dh = WrTH;  dl = WrTL;  N = 1024; tK = bid >> 4; tN = bid & 15; }
    else                 { bid -= 1024; src = Wo; dh = WoTH;  dl = WoTL;  N = 1024; tK = bid >> 4; tN = bid & 15; }
    const int k0 = tK * 64, n0 = tN * 64;

    #pragma unroll
    for (int i = 0; i < 16; ++i) {
        const int idx = i * 256 + t;
        const int r = idx >> 6, c = idx & 63;
        tl[r][c] = src[(size_t)(k0 + r) * N + n0 + c];
    }
    __syncthreads();
    #pragma unroll
    for (int i = 0; i < 16; ++i) {
        const int idx = i * 256 + t;
        const int rn = idx >> 6, ck = idx & 63;
        const float x = tl[ck][rn];
        const u16 hi = f2bf(x);
        const u16 lo = f2bf(x - bf2f(hi));
        const size_t o = (size_t)(n0 + rn) * 1024 + k0 + ck;
        dh[o] = hi; dl[o] = lo;
    }
}

// ---------------------------------------------------------------------------
// bf16 MFMA GEMM (unchanged from round 5). Pass counts: mode1 3, K 2, V 1,
// mode3 2, mode4 3. V stored TRANSPOSED [bh][d][key].
// ---------------------------------------------------------------------------
__global__ __launch_bounds__(256)
void gemm_mfma(const u16* __restrict__ fullH, const u16* __restrict__ fullL,
               const u16* __restrict__ relH,  const u16* __restrict__ relL,
               const u16* __restrict__ WqTH,  const u16* __restrict__ WqTL,
               const u16* __restrict__ WkvTH, const u16* __restrict__ WkvTL,
               const u16* __restrict__ WrTH,  const u16* __restrict__ WrTL,
               const u16* __restrict__ atH,   const u16* __restrict__ atL,
               const u16* __restrict__ WoTH,  const u16* __restrict__ WoTL,
               const float* __restrict__ bias_c,
               float* __restrict__ qc, u16* __restrict__ kb16, u16* __restrict__ vT16,
               u16* __restrict__ rb16, float* __restrict__ outp, int base)
{
    __shared__ uint4 ldsbuf[2048];           // 32 KB: Ah | Al | Bh | Bl
    char* lds = (char*)ldsbuf;

    int bid = blockIdx.x;
    int mode, m0, n0, arow0, npass;
    const u16 *aH, *aL, *bH, *bL;
    if (base == 4) {
        mode = 4; m0 = (bid >> 3) * 128; n0 = (bid & 7) * 128;
        aH = atH; aL = atL; bH = WoTH; bL = WoTL; arow0 = m0; npass = 3;
    } else if (bid < 128) {
        mode = 1; m0 = (bid >> 3) * 128; n0 = (bid & 7) * 128;
        aH = fullH; aL = fullL; bH = WqTH; bL = WqTL;
        arow0 = (m0 >> 10) * cK + cM + (m0 & (cQ - 1)); npass = 3;
    } else if (bid < 640) {
        bid -= 128; mode = 2; m0 = (bid >> 4) * 128; n0 = (bid & 15) * 128;
        aH = fullH; aL = fullL; bH = WkvTH; bL = WkvTL; arow0 = m0;
        npass = (n0 >= cU) ? 1 : 2;
    } else {
        bid -= 640; mode = 3; m0 = (bid >> 3) * 128; n0 = (bid & 7) * 128;
        aH = relH; aL = relL; bH = WrTH; bL = WrTL; arow0 = m0; npass = 2;
    }

    const int t = threadIdx.x, w = t >> 6, lane = t & 63;

    const int rl = lane >> 2;
    const int cl = (lane & 3) ^ ((lane >> 3) & 3);  // XOR-swizzled chunk
    const u16* src;
    if (w == 0)      src = aH + (size_t)(arow0 + rl) * 1024 + cl * 8;
    else if (w == 1) src = aL + (size_t)(arow0 + rl) * 1024 + cl * 8;
    else if (w == 2) src = bH + (size_t)(n0 + rl) * 1024 + cl * 8;
    else             src = bL + (size_t)(n0 + rl) * 1024 + cl * 8;
    char* ldsw = lds + w * 8192;
    const bool doStage = (w == 0) || (w == 2) || (w == 1 && npass >= 2) || (w == 3 && npass >= 3);

    const int l31 = lane & 31, hk = lane >> 5;
    const int fsw = (l31 >> 1) & 3;
    const int koff[2] = { ((hk ^ fsw) << 4), (((2 + hk) ^ fsw) << 4) };
    const int mwb = (w >> 1) * 4096 + l31 * 64;
    const int nwb = (w & 1) * 4096 + l31 * 64;

    v16f acc[2][2];
    #pragma unroll
    for (int i = 0; i < 16; ++i) { acc[0][0][i] = 0.f; acc[0][1][i] = 0.f; acc[1][0][i] = 0.f; acc[1][1][i] = 0.f; }

    for (int kit = 0; kit < 32; ++kit) {
        __syncthreads();
        if (doStage) {
            #pragma unroll
            for (int g = 0; g < 8; ++g)
                __builtin_amdgcn_global_load_lds((gp1)(src + (size_t)g * 16 * 1024),
                                                 (lp3)(ldsw + g * 1024), 16, 0, 0);
        }
        src += 32;
        __syncthreads();

        #pragma unroll
        for (int s = 0; s < 2; ++s) {
            const int ko = koff[s];
            const v8bf ah0 = *(const v8bf*)(lds + mwb + ko);
            const v8bf ah1 = *(const v8bf*)(lds + mwb + 2048 + ko);
            const v8bf bh0 = *(const v8bf*)(lds + 16384 + nwb + ko);
            const v8bf bh1 = *(const v8bf*)(lds + 16384 + nwb + 2048 + ko);
            acc[0][0] = MFMA32(ah0, bh0, acc[0][0]);
            acc[0][1] = MFMA32(ah0, bh1, acc[0][1]);
            acc[1][0] = MFMA32(ah1, bh0, acc[1][0]);
            acc[1][1] = MFMA32(ah1, bh1, acc[1][1]);
            if (npass >= 2) {
                const v8bf al0 = *(const v8bf*)(lds + 8192 + mwb + ko);
                const v8bf al1 = *(const v8bf*)(lds + 8192 + mwb + 2048 + ko);
                acc[0][0] = MFMA32(al0, bh0, acc[0][0]);
                acc[0][1] = MFMA32(al0, bh1, acc[0][1]);
                acc[1][0] = MFMA32(al1, bh0, acc[1][0]);
                acc[1][1] = MFMA32(al1, bh1, acc[1][1]);
            }
            if (npass >= 3) {
                const v8bf bl0 = *(const v8bf*)(lds + 24576 + nwb + ko);
                const v8bf bl1 = *(const v8bf*)(lds + 24576 + nwb + 2048 + ko);
                acc[0][0] = MFMA32(ah0, bl0, acc[0][0]);
                acc[0][1] = MFMA32(ah0, bl1, acc[0][1]);
                acc[1][0] = MFMA32(ah1, bl0, acc[1][0]);
                acc[1][1] = MFMA32(ah1, bl1, acc[1][1]);
            }
        }
    }

    #pragma unroll
    for (int mi = 0; mi < 2; ++mi)
    #pragma unroll
    for (int ni = 0; ni < 2; ++ni) {
        const int n = n0 + (w & 1) * 64 + ni * 32 + l31;
        #pragma unroll
        for (int e = 0; e < 16; ++e) {
            const int m = m0 + (w >> 1) * 64 + mi * 32 + (e & 3) + 8 * (e >> 2) + 4 * hk;
            const float v = acc[mi][ni][e];
            if (mode == 1) {
                const int b = m >> 10, q = m & (cQ - 1);
                const int h = n >> 6, d = n & 63;
                qc[(((size_t)(b * cH + h)) * cQ + q) * cD + d] = v + bias_c[n];
            } else if (mode == 2) {
                const int b = m >> 11, l = m & (cK - 1);
                const int nn = n & (cU - 1);
                const int h = nn >> 6, d = nn & 63;
                if (n >= cU)
                    vT16[(((size_t)(b * cH + h)) * cD + d) * cK + l] = f2bf(v);
                else
                    kb16[(((size_t)(b * cH + h)) * cK + l) * cD + d] = f2bf(v);
            } else if (mode == 3) {
                const int b = m >> 11, l = m & (cK - 1);
                const int h = n >> 6, d = n & 63;
                rb16[(((size_t)(b * cH + h)) * cK + l) * cD + d] = f2bf(v);
            } else {
                outp[(size_t)m * cU + n] = v;
            }
        }
    }
}

// ---------------------------------------------------------------------------
// wvec: w_all[bh][win] = sum_d r[bh][win][d] * (bias_r - bias_c)[h][d]
// ---------------------------------------------------------------------------
__global__ __launch_bounds__(256)
void wvec_kernel(const u16* __restrict__ rb16, const float* __restrict__ bias_c,
                 const float* __restrict__ bias_r, float* __restrict__ w_all)
{
    const int t = threadIdx.x, w = t >> 6, lane = t & 63;
    #pragma unroll 4
    for (int it = 0; it < 16; ++it) {
        const int row = blockIdx.x * 64 + it * 4 + w;    // 65536 rows
        const int bh = row >> 11, win = row & (cK - 1);
        const int h = bh & (cH - 1);
        const float d = bias_r[h * 64 + lane] - bias_c[h * 64 + lane];
        float v = bf2f(rb16[(size_t)row * 64 + lane]) * d;
        #pragma unroll
        for (int off = 1; off <= 32; off <<= 1)
            v += __shfl_xor(v, off);
        if (lane == 0) w_all[(size_t)bh * cWPAD + win] = v;
    }
}

// ---------------------------------------------------------------------------
// MFMA flash attention round 6: K/R staged in LDS (padded, 2-way-free) with
// global->REGISTER double-buffering (next chunk's loads in flight across the
// whole current chunk); V direct-global (transposed) prefetched at chunk top;
// SrelT in bf16 with the delta.r window term folded at write time.
// LDS 51.5 KB -> 3 blocks/CU; 3 barriers/chunk; split-K x2 (1024 blocks).
// ---------------------------------------------------------------------------
__global__ __launch_bounds__(256, 3)
void flash_mfma(const float* __restrict__ qcg, const u16* __restrict__ kbg,
                const u16* __restrict__ vTg, const u16* __restrict__ rbg,
                const float* __restrict__ w_all,
                float* __restrict__ oPart, float* __restrict__ lPart)
{
    __shared__ u16 Kh[64][68];        // [key][dh]
    __shared__ u16 Rh[128][68];       // [window][dh]
    __shared__ u16 SrelT[128][68];    // [window][q-row] bf16, wv folded in
    __shared__ u16 Ph[64][68];        // [q-row][key]
    __shared__ float lrow[2][64];     // total 52,736 B -> 3 blocks/CU

    const int bid = blockIdx.x;
    const int hb = bid & 31;
    const int inner = bid >> 5;
    const int qb = inner & 15;
    const int sp = inner >> 4;         // split 0/1
    const int h = hb >> 1, b = hb & 1;
    const int bh = b * cH + h;
    const int q0 = qb * 64;

    const u16* kg = kbg + (size_t)bh * cK * cD;
    const u16* vg = vTg + (size_t)bh * cD * cK;
    const u16* rg = rbg + (size_t)bh * cK * cD;
    const float* qg = qcg + (size_t)bh * cQ * cD;
    const float* wg = w_all + (size_t)bh * cWPAD;

    const int t = threadIdx.x, w = t >> 6, lane = t & 63;
    const int l31 = lane & 31, hk = lane >> 5;
    const int rloc0 = (w >> 1) * 32;
    const int c0 = (w & 1) * 32;
    const int wc0 = (w & 1) * 64 + l31;

    // Q fragments hi/lo (A-operand rows rloc0+l31)
    Frag qch[4], qcl[4];
    {
        const float* qrow = qg + (size_t)(q0 + rloc0 + l31) * cD;
        #pragma unroll
        for (int kc = 0; kc < 4; ++kc) {
            const int dh0 = kc * 16 + hk * 8;
            const float4 f0 = *(const float4*)(qrow + dh0);
            const float4 f1 = *(const float4*)(qrow + dh0 + 4);
            const float xs[8] = {f0.x, f0.y, f0.z, f0.w, f1.x, f1.y, f1.z, f1.w};
            #pragma unroll
            for (int j = 0; j < 8; ++j) {
                const u16 xh = f2bf(xs[j]);
                qch[kc].s[j] = xh;
                qcl[kc].s[j] = f2bf(xs[j] - bf2f(xh));
            }
        }
    }

    v16f aO;
    float lpart[16];
    #pragma unroll
    for (int i = 0; i < 16; ++i) { aO[i] = 0.f; lpart[i] = 0.f; }

    const int nch = 17 + qb;
    int j0 = sp * 64;

    // register staging buffers (K: 2x uint4/thread, R: 4x uint4/thread)
    uint4 kpre[2], rpre[4];
    {
        const int relb = j0 - q0 + 960;
        #pragma unroll
        for (int i = 0; i < 2; ++i) {
            const int u = t + 256 * i;
            kpre[i] = *(const uint4*)(kg + (size_t)(j0 + (u >> 3)) * cD + (u & 7) * 8);
        }
        #pragma unroll
        for (int i = 0; i < 4; ++i) {
            const int u = t + 256 * i;
            rpre[i] = *(const uint4*)(rg + (size_t)(relb + (u >> 3)) * cD + (u & 7) * 8);
        }
    }

    for (int c = sp; c < nch; c += 2) {
        const int relbase = j0 - q0 + 960;

        // V prefetch (current chunk, direct-global transposed) + wv loads
        Frag vf[4];
        #pragma unroll
        for (int kc = 0; kc < 4; ++kc)
            vf[kc].q4 = *(const uint4*)(vg + (size_t)(c0 + l31) * cK + j0 + kc * 16 + hk * 8);
        const float wv0 = wg[relbase + wc0];
        const float wv1 = wg[relbase + wc0 + 32];

        // write staged registers -> LDS
        #pragma unroll
        for (int i = 0; i < 2; ++i) {
            const int u = t + 256 * i;
            *(uint2*)&Kh[u >> 3][(u & 7) * 8]     = make_uint2(kpre[i].x, kpre[i].y);
            *(uint2*)&Kh[u >> 3][(u & 7) * 8 + 4] = make_uint2(kpre[i].z, kpre[i].w);
        }
        #pragma unroll
        for (int i = 0; i < 4; ++i) {
            const int u = t + 256 * i;
            *(uint2*)&Rh[u >> 3][(u & 7) * 8]     = make_uint2(rpre[i].x, rpre[i].y);
            *(uint2*)&Rh[u >> 3][(u & 7) * 8 + 4] = make_uint2(rpre[i].z, rpre[i].w);
        }
        __syncthreads();   // A: staging visible

        // issue next chunk's global->register loads (in flight all chunk)
        {
            const int jn = (c + 2 < nch) ? j0 + 128 : j0;
            const int relbn = jn - q0 + 960;
            #pragma unroll
            for (int i = 0; i < 2; ++i) {
                const int u = t + 256 * i;
                kpre[i] = *(const uint4*)(kg + (size_t)(jn + (u >> 3)) * cD + (u & 7) * 8);
            }
            #pragma unroll
            for (int i = 0; i < 4; ++i) {
                const int u = t + 256 * i;
                rpre[i] = *(const uint4*)(rg + (size_t)(relbn + (u >> 3)) * cD + (u & 7) * 8);
            }
        }

        // ---- S phase: ctx + rel MFMA from LDS
        v16f actx, ar0, ar1;
        #pragma unroll
        for (int i = 0; i < 16; ++i) { actx[i] = 0.f; ar0[i] = 0.f; ar1[i] = 0.f; }
        #pragma unroll
        for (int kc = 0; kc < 4; ++kc) {
            const int kb0 = kc * 16 + hk * 8;
            Frag kf, rf0, rf1;
            kf.d2[0]  = *(const uint2*)&Kh[c0 + l31][kb0];
            kf.d2[1]  = *(const uint2*)&Kh[c0 + l31][kb0 + 4];
            rf0.d2[0] = *(const uint2*)&Rh[wc0][kb0];
            rf0.d2[1] = *(const uint2*)&Rh[wc0][kb0 + 4];
            rf1.d2[0] = *(const uint2*)&Rh[wc0 + 32][kb0];
            rf1.d2[1] = *(const uint2*)&Rh[wc0 + 32][kb0 + 4];
            actx = MFMA32(qch[kc].v, kf.v, actx);
            actx = MFMA32(qcl[kc].v, kf.v, actx);
            ar0  = MFMA32(qch[kc].v, rf0.v, ar0);
            ar0  = MFMA32(qcl[kc].v, rf0.v, ar0);
            ar1  = MFMA32(qch[kc].v, rf1.v, ar1);
            ar1  = MFMA32(qcl[kc].v, rf1.v, ar1);
        }
        // write SrelT (bf16, wv folded); lane col = window wc0, rows packed x4
        #pragma unroll
        for (int g = 0; g < 4; ++g) {
            const int rb_ = rloc0 + 8 * g + 4 * hk;
            u16 p0[4], p1[4];
            #pragma unroll
            for (int e = 0; e < 4; ++e) {
                p0[e] = f2bf(ar0[4 * g + e] + wv0);
                p1[e] = f2bf(ar1[4 * g + e] + wv1);
            }
            *(uint2*)&SrelT[wc0][rb_]      = make_uint2(p0[0] | ((u32)p0[1] << 16),
                                                        p0[2] | ((u32)p0[3] << 16));
            *(uint2*)&SrelT[wc0 + 32][rb_] = make_uint2(p1[0] | ((u32)p1[1] << 16),
                                                        p1[2] | ((u32)p1[3] << 16));
        }
        __syncthreads();   // B: SrelT visible

        // ---- gather + exp (fixed offset) + Ph write
        const int jl = c0 + l31;
        const int limit = cM + q0 - j0;
        float pvv[16];
        #pragma unroll
        for (int g = 0; g < 4; ++g)
        #pragma unroll
        for (int e = 0; e < 4; ++e) {
            const int reg  = 4 * g + e;
            const int rloc = rloc0 + e + 8 * g + 4 * hk;
            const int widx = jl - rloc + 63;            // [0,126]
            const float srel = bf2f(SrelT[widx][rloc]);
            const float s = (actx[reg] + srel) * 0.125f - 10.f;
            const float p = (jl > limit + rloc) ? 0.f : __expf(s);
            lpart[reg] += p;
            pvv[reg] = p;
        }
        #pragma unroll
        for (int g = 0; g < 4; ++g)
        #pragma unroll
        for (int e = 0; e < 4; ++e)
            Ph[rloc0 + e + 8 * g + 4 * hk][jl] = f2bf(pvv[4 * g + e]);
        __syncthreads();   // C: Ph visible

        // ---- PV (P from LDS, V from registers)
        #pragma unroll
        for (int kc = 0; kc < 4; ++kc) {
            const int kb0 = kc * 16 + hk * 8;
            Frag pf;
            pf.d2[0] = *(const uint2*)&Ph[rloc0 + l31][kb0];
            pf.d2[1] = *(const uint2*)&Ph[rloc0 + l31][kb0 + 4];
            aO = MFMA32(pf.v, vf[kc].v, aO);
        }
        j0 += 128;
    }

    // ---- denominators
    #pragma unroll
    for (int off = 1; off <= 16; off <<= 1)
        #pragma unroll
        for (int i = 0; i < 16; ++i) lpart[i] += __shfl_xor(lpart[i], off);
    if (l31 == 0) {
        #pragma unroll
        for (int g = 0; g < 4; ++g)
        #pragma unroll
        for (int e = 0; e < 4; ++e)
            lrow[w & 1][rloc0 + e + 8 * g + 4 * hk] = lpart[4 * g + e];
    }
    __syncthreads();

    // ---- store unnormalized O part + l part
    float* ob = oPart + (size_t)sp * ((size_t)cB * cQ * cU);
    #pragma unroll
    for (int g = 0; g < 4; ++g)
    #pragma unroll
    for (int e = 0; e < 4; ++e) {
        const int reg  = 4 * g + e;
        const int rloc = rloc0 + e + 8 * g + 4 * hk;
        ob[((size_t)(b * cQ + q0 + rloc)) * cU + h * 64 + c0 + l31] = aO[reg];
    }
    if (t < 64)
        lPart[(size_t)sp * (cB * cH * cQ) + (size_t)bh * cQ + q0 + t] = lrow[0][t] + lrow[1][t];
}

// ---------------------------------------------------------------------------
// combine: o = (o0+o1)/(l0+l1), write bf16 hi/lo for the out-GEMM.
// ---------------------------------------------------------------------------
__global__ __launch_bounds__(256)
void combine(const float* __restrict__ oPart, const float* __restrict__ lPart,
             u16* __restrict__ atH, u16* __restrict__ atL)
{
    const int idx = blockIdx.x * 256 + threadIdx.x;
    const size_t base = (size_t)idx * 4;
    const int b = (int)(base >> 20);
    const int rem = (int)(base & ((1u << 20) - 1));
    const int q = rem >> 10;
    const int u = rem & 1023;
    const int h = u >> 6;
    const float4 o0 = *(const float4*)(oPart + base);
    const float4 o1 = *(const float4*)(oPart + (size_t)cB * cQ * cU + base);
    const int li = (b * cH + h) * cQ + q;
    const float l = lPart[li] + lPart[cB * cH * cQ + li];
    const float inv = 1.f / l;
    const float vals[4] = {(o0.x + o1.x) * inv, (o0.y + o1.y) * inv,
                           (o0.z + o1.z) * inv, (o0.w + o1.w) * inv};
    u16 hi[4], lo[4];
    #pragma unroll
    for (int j = 0; j < 4; ++j) {
        hi[j] = f2bf(vals[j]);
        lo[j] = f2bf(vals[j] - bf2f(hi[j]));
    }
    uint2 ph, pl;
    ph.x = hi[0] | ((u32)hi[1] << 16); ph.y = hi[2] | ((u32)hi[3] << 16);
    pl.x = lo[0] | ((u32)lo[1] << 16); pl.y = lo[2] | ((u32)lo[3] << 16);
    *(uint2*)(atH + base) = ph;
    *(uint2*)(atL + base) = pl;
}

// ---------------------------------------------------------------------------
extern "C" void kernel_launch(void* const* d_in, const int* in_sizes, int n_in,
                              void* d_out, int out_size, void* d_ws, size_t ws_size,
                              hipStream_t stream)
{
    const float* inputs    = (const float*)d_in[0];
    const float* relatives = (const float*)d_in[1];
    const float* memories  = (const float*)d_in[2];
    const float* bias_c    = (const float*)d_in[3];
    const float* bias_r    = (const float*)d_in[4];
    const float* Wq        = (const float*)d_in[5];
    const float* Wkv       = (const float*)d_in[6];
    const float* Wr        = (const float*)d_in[7];
    const float* Wo        = (const float*)d_in[8];
    float* out = (float*)d_out;

    char* p = (char*)d_ws;
    auto alloc = [&](size_t bytes) { char* r = p; p += bytes; return r; };
    u16* fullH = (u16*)alloc(8u << 20);
    u16* fullL = (u16*)alloc(8u << 20);
    u16* relH  = (u16*)alloc(8u << 20);   // oPart aliases relH+relL after proj
    u16* relL  = (u16*)alloc(8u << 20);
    u16* WqTH  = (u16*)alloc(2u << 20);
    u16* WqTL  = (u16*)alloc(2u << 20);
    u16* WkvTH = (u16*)alloc(4u << 20);
    u16* WkvTL = (u16*)alloc(4u << 20);
    u16* WrTH  = (u16*)alloc(2u << 20);
    u16* WrTL  = (u16*)alloc(2u << 20);
    u16* WoTH  = (u16*)alloc(2u << 20);
    u16* WoTL  = (u16*)alloc(2u << 20);
    float* qc  = (float*)alloc(8u << 20);
    u16* kb16  = (u16*)alloc(8u << 20);
    u16* vT16  = (u16*)alloc(8u << 20);
    u16* rb16  = (u16*)alloc(8u << 20);
    float* w_all = (float*)alloc(32u * cWPAD * 4u);
    float* lPart = (float*)alloc(2u * cB * cH * cQ * 4u);
    u16* atH   = (u16*)alloc(4u << 20);
    u16* atL   = (u16*)alloc(4u << 20);
    float* oPart = (float*)relH;          // 16 MB, reuses rel planes

    convert_acts<<<8192, 256, 0, stream>>>(inputs, memories, relatives,
                                           fullH, fullL, relH, relL);
    convert_wT<<<1280, 256, 0, stream>>>(Wq, Wkv, Wr, Wo,
                                         WqTH, WqTL, WkvTH, WkvTL,
                                         WrTH, WrTL, WoTH, WoTL);
    gemm_mfma<<<896, 256, 0, stream>>>(fullH, fullL, relH, relL,
                                       WqTH, WqTL, WkvTH, WkvTL, WrTH, WrTL,
                                       atH, atL, WoTH, WoTL, bias_c,
                                       qc, kb16, vT16, rb16, out, 0);
    wvec_kernel<<<1024, 256, 0, stream>>>(rb16, bias_c, bias_r, w_all);
    flash_mfma<<<1024, 256, 0, stream>>>(qc, kb16, vT16, rb16, w_all, oPart, lPart);
    combine<<<2048, 256, 0, stream>>>(oPart, lPart, atH, atL);
    gemm_mfma<<<128, 256, 0, stream>>>(fullH, fullL, relH, relL,
                                       WqTH, WqTL, WkvTH, WkvTL, WrTH, WrTL,
                                       atH, atL, WoTH, WoTL, bias_c,
                                       qc, kb16, vT16, rb16, out, 4);
}

// Round 7
// 342.343 us; speedup vs baseline: 1.3202x; 1.3202x over previous
//
#include <hip/hip_runtime.h>
#include <math.h>
#include <stdint.h>

using u16 = unsigned short;
using u32 = uint32_t;

// Problem constants
constexpr int cB = 2;
constexpr int cQ = 1024;
constexpr int cM = 1024;
constexpr int cU = 1024;
constexpr int cH = 16;
constexpr int cD = 64;
constexpr int cK = 2048;    // KLEN
constexpr int cRROWS = 2112; // R fragment buffer rows (covers OOB window to 2111)
constexpr int cWPAD = 2176;  // w_all row stride

typedef __bf16 v8bf  __attribute__((ext_vector_type(8)));
typedef float  v16f  __attribute__((ext_vector_type(16)));

#define MFMA32(a, b, c) __builtin_amdgcn_mfma_f32_32x32x16_bf16((a), (b), (c), 0, 0, 0)

__device__ __forceinline__ u16 f2bf(float f) {   // RTN float->bf16 bits
    u32 u = __float_as_uint(f);
    u += 0x7fffu + ((u >> 16) & 1u);
    return (u16)(u >> 16);
}
__device__ __forceinline__ float bf2f(u16 s) {
    return __uint_as_float(((u32)s) << 16);
}

union Frag { v8bf v; u16 s[8]; uint2 d2[2]; uint4 q4; };

typedef const u32 __attribute__((address_space(1)))* gp1;
typedef u32 __attribute__((address_space(3)))* lp3;

// ---------------------------------------------------------------------------
// Convert activations to bf16 hi/lo planes (unchanged).
// ---------------------------------------------------------------------------
__global__ __launch_bounds__(256)
void convert_acts(const float* __restrict__ inputs, const float* __restrict__ memories,
                  const float* __restrict__ relatives,
                  u16* __restrict__ fullH, u16* __restrict__ fullL,
                  u16* __restrict__ relH,  u16* __restrict__ relL)
{
    const int idx = blockIdx.x * 256 + threadIdx.x;
    const float* src;
    u16 *dh, *dl;
    int q;
    if (idx < (1 << 20)) {                            // full = concat(mem, inp)
        q = idx;
        const int row = q >> 8;
        const int col = (q & 255) * 4;
        const int b = row >> 11, l = row & (cK - 1);
        src = (l < cM) ? (memories + ((size_t)b * cM + l) * cU + col)
                       : (inputs   + ((size_t)b * cQ + (l - cM)) * cU + col);
        dh = fullH; dl = fullL;
    } else {
        q = idx - (1 << 20);
        src = relatives + (size_t)q * 4;
        dh = relH; dl = relL;
    }
    const float4 f = *(const float4*)src;
    const float xs[4] = {f.x, f.y, f.z, f.w};
    u16 hi[4], lo[4];
    #pragma unroll
    for (int j = 0; j < 4; ++j) {
        hi[j] = f2bf(xs[j]);
        lo[j] = f2bf(xs[j] - bf2f(hi[j]));
    }
    uint2 ph, pl;
    ph.x = hi[0] | ((u32)hi[1] << 16); ph.y = hi[2] | ((u32)hi[3] << 16);
    pl.x = lo[0] | ((u32)lo[1] << 16); pl.y = lo[2] | ((u32)lo[3] << 16);
    *(uint2*)(dh + (size_t)q * 4) = ph;
    *(uint2*)(dl + (size_t)q * 4) = pl;
}

// ---------------------------------------------------------------------------
// Convert + TRANSPOSE weights to bf16 hi/lo (unchanged).
// ---------------------------------------------------------------------------
__global__ __launch_bounds__(256)
void convert_wT(const float* __restrict__ Wq, const float* __restrict__ Wkv,
                const float* __restrict__ Wr, const float* __restrict__ Wo,
                u16* __restrict__ WqTH, u16* __restrict__ WqTL,
                u16* __restrict__ WkvTH, u16* __restrict__ WkvTL,
                u16* __restrict__ WrTH, u16* __restrict__ WrTL,
                u16* __restrict__ WoTH, u16* __restrict__ WoTL)
{
    __shared__ float tl[64][65];
    const int t = threadIdx.x;
    int bid = blockIdx.x;
    const float* src; u16 *dh, *dl; int N, tK, tN;
    if (bid < 256)       { src = Wq;  dh = WqTH;  dl = WqTL;  N = 1024; tK = bid >> 4; tN = bid & 15; }
    else if (bid < 768)  { bid -= 256; src = Wkv; dh = WkvTH; dl = WkvTL; N = 2048; tK = bid >> 5; tN = bid & 31; }
    else if (bid < 1024) { bid -= 768; src = Wr;  dh = WrTH;  dl = WrTL;  N = 1024; tK = bid >> 4; tN = bid & 15; }
    else                 { bid -= 1024; src = Wo; dh = WoTH;  dl = WoTL;  N = 1024; tK = bid >> 4; tN = bid & 15; }
    const int k0 = tK * 64, n0 = tN * 64;

    #pragma unroll
    for (int i = 0; i < 16; ++i) {
        const int idx = i * 256 + t;
        const int r = idx >> 6, c = idx & 63;
        tl[r][c] = src[(size_t)(k0 + r) * N + n0 + c];
    }
    __syncthreads();
    #pragma unroll
    for (int i = 0; i < 16; ++i) {
        const int idx = i * 256 + t;
        const int rn = idx >> 6, ck = idx & 63;
        const float x = tl[ck][rn];
        const u16 hi = f2bf(x);
        const u16 lo = f2bf(x - bf2f(hi));
        const size_t o = (size_t)(n0 + rn) * 1024 + k0 + ck;
        dh[o] = hi; dl[o] = lo;
    }
}

// ---------------------------------------------------------------------------
// bf16 MFMA GEMM. Pass counts: mode1 3, K 2, V 1, mode3 2, mode4 3.
// K, V, R stored in MFMA-FRAGMENT-LINEAR order for flash:
//   K (B-op, col=key,k=dh):  idx = (l>>6)*4096 + (d>>4)*1024 + ((d>>3)&1)*512 + (l&63)*8 + (d&7)
//   V (B-op, col=dh,k=key):  idx = (l>>6)*4096 + ((l>>4)&3)*1024 + ((l>>3)&1)*512 + d*8 + (l&7)
//   R (B-op, col=row,k=dh):  idx = (g>>5)*2048 + (d>>4)*512 + ((d>>3)&1)*256 + (g&31)*8 + (d&7)
// ---------------------------------------------------------------------------
__global__ __launch_bounds__(256)
void gemm_mfma(const u16* __restrict__ fullH, const u16* __restrict__ fullL,
               const u16* __restrict__ relH,  const u16* __restrict__ relL,
               const u16* __restrict__ WqTH,  const u16* __restrict__ WqTL,
               const u16* __restrict__ WkvTH, const u16* __restrict__ WkvTL,
               const u16* __restrict__ WrTH,  const u16* __restrict__ WrTL,
               const u16* __restrict__ atH,   const u16* __restrict__ atL,
               const u16* __restrict__ WoTH,  const u16* __restrict__ WoTL,
               const float* __restrict__ bias_c,
               float* __restrict__ qc, u16* __restrict__ kb16, u16* __restrict__ vb16,
               u16* __restrict__ rb16, float* __restrict__ outp, int base)
{
    __shared__ uint4 ldsbuf[2048];           // 32 KB: Ah | Al | Bh | Bl
    char* lds = (char*)ldsbuf;

    int bid = blockIdx.x;
    int mode, m0, n0, arow0, npass;
    const u16 *aH, *aL, *bH, *bL;
    if (base == 4) {
        mode = 4; m0 = (bid >> 3) * 128; n0 = (bid & 7) * 128;
        aH = atH; aL = atL; bH = WoTH; bL = WoTL; arow0 = m0; npass = 3;
    } else if (bid < 128) {
        mode = 1; m0 = (bid >> 3) * 128; n0 = (bid & 7) * 128;
        aH = fullH; aL = fullL; bH = WqTH; bL = WqTL;
        arow0 = (m0 >> 10) * cK + cM + (m0 & (cQ - 1)); npass = 3;
    } else if (bid < 640) {
        bid -= 128; mode = 2; m0 = (bid >> 4) * 128; n0 = (bid & 15) * 128;
        aH = fullH; aL = fullL; bH = WkvTH; bL = WkvTL; arow0 = m0;
        npass = (n0 >= cU) ? 1 : 2;
    } else {
        bid -= 640; mode = 3; m0 = (bid >> 3) * 128; n0 = (bid & 7) * 128;
        aH = relH; aL = relL; bH = WrTH; bL = WrTL; arow0 = m0; npass = 2;
    }

    const int t = threadIdx.x, w = t >> 6, lane = t & 63;

    const int rl = lane >> 2;
    const int cl = (lane & 3) ^ ((lane >> 3) & 3);  // XOR-swizzled chunk
    const u16* src;
    if (w == 0)      src = aH + (size_t)(arow0 + rl) * 1024 + cl * 8;
    else if (w == 1) src = aL + (size_t)(arow0 + rl) * 1024 + cl * 8;
    else if (w == 2) src = bH + (size_t)(n0 + rl) * 1024 + cl * 8;
    else             src = bL + (size_t)(n0 + rl) * 1024 + cl * 8;
    char* ldsw = lds + w * 8192;
    const bool doStage = (w == 0) || (w == 2) || (w == 1 && npass >= 2) || (w == 3 && npass >= 3);

    const int l31 = lane & 31, hk = lane >> 5;
    const int fsw = (l31 >> 1) & 3;
    const int koff[2] = { ((hk ^ fsw) << 4), (((2 + hk) ^ fsw) << 4) };
    const int mwb = (w >> 1) * 4096 + l31 * 64;
    const int nwb = (w & 1) * 4096 + l31 * 64;

    v16f acc[2][2];
    #pragma unroll
    for (int i = 0; i < 16; ++i) { acc[0][0][i] = 0.f; acc[0][1][i] = 0.f; acc[1][0][i] = 0.f; acc[1][1][i] = 0.f; }

    for (int kit = 0; kit < 32; ++kit) {
        __syncthreads();
        if (doStage) {
            #pragma unroll
            for (int g = 0; g < 8; ++g)
                __builtin_amdgcn_global_load_lds((gp1)(src + (size_t)g * 16 * 1024),
                                                 (lp3)(ldsw + g * 1024), 16, 0, 0);
        }
        src += 32;
        __syncthreads();

        #pragma unroll
        for (int s = 0; s < 2; ++s) {
            const int ko = koff[s];
            const v8bf ah0 = *(const v8bf*)(lds + mwb + ko);
            const v8bf ah1 = *(const v8bf*)(lds + mwb + 2048 + ko);
            const v8bf bh0 = *(const v8bf*)(lds + 16384 + nwb + ko);
            const v8bf bh1 = *(const v8bf*)(lds + 16384 + nwb + 2048 + ko);
            acc[0][0] = MFMA32(ah0, bh0, acc[0][0]);
            acc[0][1] = MFMA32(ah0, bh1, acc[0][1]);
            acc[1][0] = MFMA32(ah1, bh0, acc[1][0]);
            acc[1][1] = MFMA32(ah1, bh1, acc[1][1]);
            if (npass >= 2) {
                const v8bf al0 = *(const v8bf*)(lds + 8192 + mwb + ko);
                const v8bf al1 = *(const v8bf*)(lds + 8192 + mwb + 2048 + ko);
                acc[0][0] = MFMA32(al0, bh0, acc[0][0]);
                acc[0][1] = MFMA32(al0, bh1, acc[0][1]);
                acc[1][0] = MFMA32(al1, bh0, acc[1][0]);
                acc[1][1] = MFMA32(al1, bh1, acc[1][1]);
            }
            if (npass >= 3) {
                const v8bf bl0 = *(const v8bf*)(lds + 24576 + nwb + ko);
                const v8bf bl1 = *(const v8bf*)(lds + 24576 + nwb + 2048 + ko);
                acc[0][0] = MFMA32(ah0, bl0, acc[0][0]);
                acc[0][1] = MFMA32(ah0, bl1, acc[0][1]);
                acc[1][0] = MFMA32(ah1, bl0, acc[1][0]);
                acc[1][1] = MFMA32(ah1, bl1, acc[1][1]);
            }
        }
    }

    #pragma unroll
    for (int mi = 0; mi < 2; ++mi)
    #pragma unroll
    for (int ni = 0; ni < 2; ++ni) {
        const int n = n0 + (w & 1) * 64 + ni * 32 + l31;
        #pragma unroll
        for (int e = 0; e < 16; ++e) {
            const int m = m0 + (w >> 1) * 64 + mi * 32 + (e & 3) + 8 * (e >> 2) + 4 * hk;
            const float v = acc[mi][ni][e];
            if (mode == 1) {
                const int b = m >> 10, q = m & (cQ - 1);
                const int h = n >> 6, d = n & 63;
                qc[(((size_t)(b * cH + h)) * cQ + q) * cD + d] = v + bias_c[n];
            } else if (mode == 2) {
                const int b = m >> 11, l = m & (cK - 1);
                const int nn = n & (cU - 1);
                const int h = nn >> 6, d = nn & 63;
                if (n >= cU)   // V fragment-linear
                    vb16[(size_t)(b * cH + h) * cK * cD + ((l >> 6) * 4096)
                         + (((l >> 4) & 3) * 1024) + (((l >> 3) & 1) * 512)
                         + d * 8 + (l & 7)] = f2bf(v);
                else           // K fragment-linear
                    kb16[(size_t)(b * cH + h) * cK * cD + ((l >> 6) * 4096)
                         + ((d >> 4) * 1024) + (((d >> 3) & 1) * 512)
                         + ((l & 63) * 8) + (d & 7)] = f2bf(v);
            } else if (mode == 3) {
                const int b = m >> 11, l = m & (cK - 1);
                const int h = n >> 6, d = n & 63;
                rb16[(size_t)(b * cH + h) * cRROWS * cD + ((l >> 5) * 2048)
                     + ((d >> 4) * 512) + (((d >> 3) & 1) * 256)
                     + ((l & 31) * 8) + (d & 7)] = f2bf(v);
            } else {
                outp[(size_t)m * cU + n] = v;
            }
        }
    }
}

// ---------------------------------------------------------------------------
// wvec: w_all[bh][win] = sum_d r[bh][win][d] * (bias_r - bias_c)[h][d]
// (reads R in fragment-linear order)
// ---------------------------------------------------------------------------
__global__ __launch_bounds__(256)
void wvec_kernel(const u16* __restrict__ rb16, const float* __restrict__ bias_c,
                 const float* __restrict__ bias_r, float* __restrict__ w_all)
{
    const int t = threadIdx.x, w = t >> 6, lane = t & 63;
    #pragma unroll 4
    for (int it = 0; it < 16; ++it) {
        const int row = blockIdx.x * 64 + it * 4 + w;    // 65536 rows
        const int bh = row >> 11, g = row & (cK - 1);
        const int h = bh & (cH - 1);
        const float d = bias_r[h * 64 + lane] - bias_c[h * 64 + lane];
        const size_t idx = (size_t)bh * cRROWS * cD + ((g >> 5) * 2048)
                         + ((lane >> 4) * 512) + (((lane >> 3) & 1) * 256)
                         + ((g & 31) * 8) + (lane & 7);
        float v = bf2f(rb16[idx]) * d;
        #pragma unroll
        for (int off = 1; off <= 32; off <<= 1)
            v += __shfl_xor(v, off);
        if (lane == 0) w_all[(size_t)bh * cWPAD + g] = v;
    }
}

// ---------------------------------------------------------------------------
// MFMA flash attention round 7: fragment-linear K/R staged via global_load_lds
// DMA (zero staging VGPRs), V as coalesced register fragments, Q hi-only
// (12 S-MFMA/chunk), 2 barriers/chunk, LDS 51.2 KB -> 3 blocks/CU, regs <=128.
// ---------------------------------------------------------------------------
__global__ __launch_bounds__(256, 4)
void flash_mfma(const float* __restrict__ qcg, const u16* __restrict__ kbg,
                const u16* __restrict__ vbg, const u16* __restrict__ rbg,
                const float* __restrict__ w_all,
                float* __restrict__ oPart, float* __restrict__ lPart)
{
    __shared__ u16 KhL[4096];        // fragment-linear K chunk (8 KB)
    __shared__ u16 RhL[8192];        // fragment-linear R window (16 KB)
    __shared__ u16 SrelT[128][68];   // [window][q-row] bf16 (wv folded)
    __shared__ u16 Ph[64][68];       // [q-row][key] bf16
    __shared__ float lrow[2][64];    // 51,712 B total -> 3 blocks/CU

    const int bid = blockIdx.x;
    const int hb = bid & 31;
    const int inner = bid >> 5;
    const int qb = inner & 15;
    const int sp = inner >> 4;         // split 0/1
    const int h = hb >> 1, b = hb & 1;
    const int bh = b * cH + h;
    const int q0 = qb * 64;

    const u16* kgf = kbg + (size_t)bh * cK * cD;
    const u16* vgf = vbg + (size_t)bh * cK * cD;
    const u16* rgf = rbg + (size_t)bh * cRROWS * cD;
    const float* qg = qcg + (size_t)bh * cQ * cD;
    const float* wg = w_all + (size_t)bh * cWPAD;

    const int t = threadIdx.x, w = t >> 6, lane = t & 63;
    const int l31 = lane & 31, hk = lane >> 5;
    const int rloc0 = (w >> 1) * 32;
    const int c0 = (w & 1) * 32;
    const int wc0 = (w & 1) * 64 + l31;

    // Q hi fragments (A-operand rows rloc0+l31)
    Frag qch[4];
    {
        const float* qrow = qg + (size_t)(q0 + rloc0 + l31) * cD;
        #pragma unroll
        for (int kc = 0; kc < 4; ++kc) {
            const int dh0 = kc * 16 + hk * 8;
            const float4 f0 = *(const float4*)(qrow + dh0);
            const float4 f1 = *(const float4*)(qrow + dh0 + 4);
            const float xs[8] = {f0.x, f0.y, f0.z, f0.w, f1.x, f1.y, f1.z, f1.w};
            #pragma unroll
            for (int j = 0; j < 8; ++j) qch[kc].s[j] = f2bf(xs[j]);
        }
    }

    v16f aO;
    float lpart[16];
    #pragma unroll
    for (int i = 0; i < 16; ++i) { aO[i] = 0.f; lpart[i] = 0.f; }

    const int nch = 17 + qb;
    int j0 = sp * 64;

    // DMA one chunk's K (8 KB) + R window (16 KB), fragment-linear, 6 instr/wave
    auto dma = [&](int jn, int relbn) {
        #pragma unroll
        for (int i = 0; i < 6; ++i) {
            const int id = w * 6 + i;
            if (id < 8) {
                const u16* s = kgf + (size_t)(jn >> 6) * 4096 + id * 512;
                __builtin_amdgcn_global_load_lds((gp1)(s + lane * 8),
                                                 (lp3)((char*)KhL + id * 1024), 16, 0, 0);
            } else {
                const int jj = id - 8;
                const u16* s = rgf + ((size_t)(relbn >> 5) + (jj >> 2)) * 2048 + (jj & 3) * 512;
                __builtin_amdgcn_global_load_lds((gp1)(s + lane * 8),
                                                 (lp3)((char*)RhL + jj * 1024), 16, 0, 0);
            }
        }
    };

    dma(j0, j0 - q0 + 960);
    __syncthreads();                 // drain prologue DMA

    for (int c = sp; c < nch; c += 2) {
        const int relbase = j0 - q0 + 960;

        // ---- V fragments (coalesced, fragment-linear) + wv window values
        Frag vf[4];
        #pragma unroll
        for (int kc = 0; kc < 4; ++kc)
            vf[kc].q4 = *(const uint4*)(vgf + (size_t)(j0 >> 6) * 4096
                                        + kc * 1024 + hk * 512 + (c0 + l31) * 8);
        const float wv0 = wg[relbase + wc0];
        const float wv1 = wg[relbase + wc0 + 32];

        // ---- S-ctx (Q hi only)
        v16f actx;
        #pragma unroll
        for (int i = 0; i < 16; ++i) actx[i] = 0.f;
        #pragma unroll
        for (int kc = 0; kc < 4; ++kc) {
            Frag kf;
            kf.q4 = *(const uint4*)(KhL + kc * 1024 + hk * 512 + (c0 + l31) * 8);
            actx = MFMA32(qch[kc].v, kf.v, actx);
        }

        // ---- S-rel in two halves (one accumulator), write SrelT (+wv)
        #pragma unroll
        for (int half = 0; half < 2; ++half) {
            v16f ar;
            #pragma unroll
            for (int i = 0; i < 16; ++i) ar[i] = 0.f;
            const int lg = (w & 1) * 2 + half;
            #pragma unroll
            for (int kc = 0; kc < 4; ++kc) {
                Frag rf;
                rf.q4 = *(const uint4*)(RhL + lg * 2048 + kc * 512 + hk * 256 + l31 * 8);
                ar = MFMA32(qch[kc].v, rf.v, ar);
            }
            const float wvh = half ? wv1 : wv0;
            const int wch = wc0 + half * 32;
            #pragma unroll
            for (int g = 0; g < 4; ++g) {
                const int rb_ = rloc0 + 8 * g + 4 * hk;
                u16 p[4];
                #pragma unroll
                for (int e = 0; e < 4; ++e) p[e] = f2bf(ar[4 * g + e] + wvh);
                *(uint2*)&SrelT[wch][rb_] = make_uint2(p[0] | ((u32)p[1] << 16),
                                                       p[2] | ((u32)p[3] << 16));
            }
        }
        __syncthreads();   // B: SrelT visible; KhL/RhL fully consumed

        // ---- DMA next chunk's K/R (lands by barrier C's vmcnt drain)
        const int jn = (c + 2 < nch) ? j0 + 128 : j0;
        dma(jn, jn - q0 + 960);

        // ---- gather + exp (fixed offset) + Ph write
        const int jl = c0 + l31;
        const int limit = cM + q0 - j0;
        #pragma unroll
        for (int g = 0; g < 4; ++g)
        #pragma unroll
        for (int e = 0; e < 4; ++e) {
            const int reg  = 4 * g + e;
            const int rloc = rloc0 + e + 8 * g + 4 * hk;
            const int widx = jl - rloc + 63;            // [0,126]
            const float srel = bf2f(SrelT[widx][rloc]);
            const float s = (actx[reg] + srel) * 0.125f - 10.f;
            const float p = (jl > limit + rloc) ? 0.f : __expf(s);
            lpart[reg] += p;
            Ph[rloc][jl] = f2bf(p);
        }
        __syncthreads();   // C: Ph visible; DMA drained -> KhL/RhL ready for next S

        // ---- PV (P from LDS, V from registers)
        #pragma unroll
        for (int kc = 0; kc < 4; ++kc) {
            const int kb0 = kc * 16 + hk * 8;
            Frag pf;
            pf.d2[0] = *(const uint2*)&Ph[rloc0 + l31][kb0];
            pf.d2[1] = *(const uint2*)&Ph[rloc0 + l31][kb0 + 4];
            aO = MFMA32(pf.v, vf[kc].v, aO);
        }
        j0 += 128;
    }

    // ---- denominators
    #pragma unroll
    for (int off = 1; off <= 16; off <<= 1)
        #pragma unroll
        for (int i = 0; i < 16; ++i) lpart[i] += __shfl_xor(lpart[i], off);
    if (l31 == 0) {
        #pragma unroll
        for (int g = 0; g < 4; ++g)
        #pragma unroll
        for (int e = 0; e < 4; ++e)
            lrow[w & 1][rloc0 + e + 8 * g + 4 * hk] = lpart[4 * g + e];
    }
    __syncthreads();

    // ---- store unnormalized O part + l part
    float* ob = oPart + (size_t)sp * ((size_t)cB * cQ * cU);
    #pragma unroll
    for (int g = 0; g < 4; ++g)
    #pragma unroll
    for (int e = 0; e < 4; ++e) {
        const int reg  = 4 * g + e;
        const int rloc = rloc0 + e + 8 * g + 4 * hk;
        ob[((size_t)(b * cQ + q0 + rloc)) * cU + h * 64 + c0 + l31] = aO[reg];
    }
    if (t < 64)
        lPart[(size_t)sp * (cB * cH * cQ) + (size_t)bh * cQ + q0 + t] = lrow[0][t] + lrow[1][t];
}

// ---------------------------------------------------------------------------
// combine: o = (o0+o1)/(l0+l1), write bf16 hi/lo for the out-GEMM.
// ---------------------------------------------------------------------------
__global__ __launch_bounds__(256)
void combine(const float* __restrict__ oPart, const float* __restrict__ lPart,
             u16* __restrict__ atH, u16* __restrict__ atL)
{
    const int idx = blockIdx.x * 256 + threadIdx.x;
    const size_t base = (size_t)idx * 4;
    const int b = (int)(base >> 20);
    const int rem = (int)(base & ((1u << 20) - 1));
    const int q = rem >> 10;
    const int u = rem & 1023;
    const int h = u >> 6;
    const float4 o0 = *(const float4*)(oPart + base);
    const float4 o1 = *(const float4*)(oPart + (size_t)cB * cQ * cU + base);
    const int li = (b * cH + h) * cQ + q;
    const float l = lPart[li] + lPart[cB * cH * cQ + li];
    const float inv = 1.f / l;
    const float vals[4] = {(o0.x + o1.x) * inv, (o0.y + o1.y) * inv,
                           (o0.z + o1.z) * inv, (o0.w + o1.w) * inv};
    u16 hi[4], lo[4];
    #pragma unroll
    for (int j = 0; j < 4; ++j) {
        hi[j] = f2bf(vals[j]);
        lo[j] = f2bf(vals[j] - bf2f(hi[j]));
    }
    uint2 ph, pl;
    ph.x = hi[0] | ((u32)hi[1] << 16); ph.y = hi[2] | ((u32)hi[3] << 16);
    pl.x = lo[0] | ((u32)lo[1] << 16); pl.y = lo[2] | ((u32)lo[3] << 16);
    *(uint2*)(atH + base) = ph;
    *(uint2*)(atL + base) = pl;
}

// ---------------------------------------------------------------------------
extern "C" void kernel_launch(void* const* d_in, const int* in_sizes, int n_in,
                              void* d_out, int out_size, void* d_ws, size_t ws_size,
                              hipStream_t stream)
{
    const float* inputs    = (const float*)d_in[0];
    const float* relatives = (const float*)d_in[1];
    const float* memories  = (const float*)d_in[2];
    const float* bias_c    = (const float*)d_in[3];
    const float* bias_r    = (const float*)d_in[4];
    const float* Wq        = (const float*)d_in[5];
    const float* Wkv       = (const float*)d_in[6];
    const float* Wr        = (const float*)d_in[7];
    const float* Wo        = (const float*)d_in[8];
    float* out = (float*)d_out;

    char* p = (char*)d_ws;
    auto alloc = [&](size_t bytes) { char* r = p; p += bytes; return r; };
    u16* fullH = (u16*)alloc(8u << 20);
    u16* fullL = (u16*)alloc(8u << 20);
    u16* relH  = (u16*)alloc(8u << 20);   // oPart aliases relH+relL after proj
    u16* relL  = (u16*)alloc(8u << 20);
    u16* WqTH  = (u16*)alloc(2u << 20);
    u16* WqTL  = (u16*)alloc(2u << 20);
    u16* WkvTH = (u16*)alloc(4u << 20);
    u16* WkvTL = (u16*)alloc(4u << 20);
    u16* WrTH  = (u16*)alloc(2u << 20);
    u16* WrTL  = (u16*)alloc(2u << 20);
    u16* WoTH  = (u16*)alloc(2u << 20);
    u16* WoTL  = (u16*)alloc(2u << 20);
    float* qc  = (float*)alloc(8u << 20);
    u16* kb16  = (u16*)alloc(8u << 20);
    u16* vb16  = (u16*)alloc(8u << 20);
    u16* rb16  = (u16*)alloc(9u << 20);   // 32 bh x 2112 rows x 64 (fragment-linear)
    float* w_all = (float*)alloc(32u * cWPAD * 4u);
    float* lPart = (float*)alloc(2u * cB * cH * cQ * 4u);
    u16* atH   = (u16*)alloc(4u << 20);
    u16* atL   = (u16*)alloc(4u << 20);
    float* oPart = (float*)relH;          // 16 MB, reuses rel planes

    convert_acts<<<8192, 256, 0, stream>>>(inputs, memories, relatives,
                                           fullH, fullL, relH, relL);
    convert_wT<<<1280, 256, 0, stream>>>(Wq, Wkv, Wr, Wo,
                                         WqTH, WqTL, WkvTH, WkvTL,
                                         WrTH, WrTL, WoTH, WoTL);
    gemm_mfma<<<896, 256, 0, stream>>>(fullH, fullL, relH, relL,
                                       WqTH, WqTL, WkvTH, WkvTL, WrTH, WrTL,
                                       atH, atL, WoTH, WoTL, bias_c,
                                       qc, kb16, vb16, rb16, out, 0);
    wvec_kernel<<<1024, 256, 0, stream>>>(rb16, bias_c, bias_r, w_all);
    flash_mfma<<<1024, 256, 0, stream>>>(qc, kb16, vb16, rb16, w_all, oPart, lPart);
    combine<<<2048, 256, 0, stream>>>(oPart, lPart, atH, atL);
    gemm_mfma<<<128, 256, 0, stream>>>(fullH, fullL, relH, relL,
                                       WqTH, WqTL, WkvTH, WkvTL, WrTH, WrTL,
                                       atH, atL, WoTH, WoTL, bias_c,
                                       qc, kb16, vb16, rb16, out, 4);
}

// Round 8
// 331.567 us; speedup vs baseline: 1.3631x; 1.0325x over previous
//
#include <hip/hip_runtime.h>
#include <math.h>
#include <stdint.h>

using u16 = unsigned short;
using u32 = uint32_t;

// Problem constants
constexpr int cB = 2;
constexpr int cQ = 1024;
constexpr int cM = 1024;
constexpr int cU = 1024;
constexpr int cH = 16;
constexpr int cD = 64;
constexpr int cK = 2048;    // KLEN
constexpr int cRROWS = 2112; // R fragment buffer rows (covers OOB window to 2111)
constexpr int cWPAD = 2176;  // w_all row stride

typedef __bf16 v8bf  __attribute__((ext_vector_type(8)));
typedef float  v16f  __attribute__((ext_vector_type(16)));

#define MFMA32(a, b, c) __builtin_amdgcn_mfma_f32_32x32x16_bf16((a), (b), (c), 0, 0, 0)

__device__ __forceinline__ u16 f2bf(float f) {   // RTN float->bf16 bits
    u32 u = __float_as_uint(f);
    u += 0x7fffu + ((u >> 16) & 1u);
    return (u16)(u >> 16);
}
__device__ __forceinline__ float bf2f(u16 s) {
    return __uint_as_float(((u32)s) << 16);
}

union Frag { v8bf v; u16 s[8]; uint2 d2[2]; uint4 q4; };

typedef const u32 __attribute__((address_space(1)))* gp1;
typedef u32 __attribute__((address_space(3)))* lp3;

// ---------------------------------------------------------------------------
// Convert activations to bf16 hi/lo planes (unchanged).
// ---------------------------------------------------------------------------
__global__ __launch_bounds__(256)
void convert_acts(const float* __restrict__ inputs, const float* __restrict__ memories,
                  const float* __restrict__ relatives,
                  u16* __restrict__ fullH, u16* __restrict__ fullL,
                  u16* __restrict__ relH,  u16* __restrict__ relL)
{
    const int idx = blockIdx.x * 256 + threadIdx.x;
    const float* src;
    u16 *dh, *dl;
    int q;
    if (idx < (1 << 20)) {                            // full = concat(mem, inp)
        q = idx;
        const int row = q >> 8;
        const int col = (q & 255) * 4;
        const int b = row >> 11, l = row & (cK - 1);
        src = (l < cM) ? (memories + ((size_t)b * cM + l) * cU + col)
                       : (inputs   + ((size_t)b * cQ + (l - cM)) * cU + col);
        dh = fullH; dl = fullL;
    } else {
        q = idx - (1 << 20);
        src = relatives + (size_t)q * 4;
        dh = relH; dl = relL;
    }
    const float4 f = *(const float4*)src;
    const float xs[4] = {f.x, f.y, f.z, f.w};
    u16 hi[4], lo[4];
    #pragma unroll
    for (int j = 0; j < 4; ++j) {
        hi[j] = f2bf(xs[j]);
        lo[j] = f2bf(xs[j] - bf2f(hi[j]));
    }
    uint2 ph, pl;
    ph.x = hi[0] | ((u32)hi[1] << 16); ph.y = hi[2] | ((u32)hi[3] << 16);
    pl.x = lo[0] | ((u32)lo[1] << 16); pl.y = lo[2] | ((u32)lo[3] << 16);
    *(uint2*)(dh + (size_t)q * 4) = ph;
    *(uint2*)(dl + (size_t)q * 4) = pl;
}

// ---------------------------------------------------------------------------
// Convert + TRANSPOSE weights to bf16 hi/lo (unchanged).
// ---------------------------------------------------------------------------
__global__ __launch_bounds__(256)
void convert_wT(const float* __restrict__ Wq, const float* __restrict__ Wkv,
                const float* __restrict__ Wr, const float* __restrict__ Wo,
                u16* __restrict__ WqTH, u16* __restrict__ WqTL,
                u16* __restrict__ WkvTH, u16* __restrict__ WkvTL,
                u16* __restrict__ WrTH, u16* __restrict__ WrTL,
                u16* __restrict__ WoTH, u16* __restrict__ WoTL)
{
    __shared__ float tl[64][65];
    const int t = threadIdx.x;
    int bid = blockIdx.x;
    const float* src; u16 *dh, *dl; int N, tK, tN;
    if (bid < 256)       { src = Wq;  dh = WqTH;  dl = WqTL;  N = 1024; tK = bid >> 4; tN = bid & 15; }
    else if (bid < 768)  { bid -= 256; src = Wkv; dh = WkvTH; dl = WkvTL; N = 2048; tK = bid >> 5; tN = bid & 31; }
    else if (bid < 1024) { bid -= 768; src = Wr;  dh = WrTH;  dl = WrTL;  N = 1024; tK = bid >> 4; tN = bid & 15; }
    else                 { bid -= 1024; src = Wo; dh = WoTH;  dl = WoTL;  N = 1024; tK = bid >> 4; tN = bid & 15; }
    const int k0 = tK * 64, n0 = tN * 64;

    #pragma unroll
    for (int i = 0; i < 16; ++i) {
        const int idx = i * 256 + t;
        const int r = idx >> 6, c = idx & 63;
        tl[r][c] = src[(size_t)(k0 + r) * N + n0 + c];
    }
    __syncthreads();
    #pragma unroll
    for (int i = 0; i < 16; ++i) {
        const int idx = i * 256 + t;
        const int rn = idx >> 6, ck = idx & 63;
        const float x = tl[ck][rn];
        const u16 hi = f2bf(x);
        const u16 lo = f2bf(x - bf2f(hi));
        const size_t o = (size_t)(n0 + rn) * 1024 + k0 + ck;
        dh[o] = hi; dl[o] = lo;
    }
}

// ---------------------------------------------------------------------------
// bf16 MFMA GEMM. Pass counts: mode1 2, K 2, V 1, mode3 2, mode4 3.
// XCD-rectangular swizzle: xcd = bid&7 selects a compact (m,n) rectangle so
// each XCD's private L2 fetches only its rectangle's A-rows + B-rows.
// K, V, R stored in MFMA-FRAGMENT-LINEAR order for flash (see round 7).
// ---------------------------------------------------------------------------
__global__ __launch_bounds__(256)
void gemm_mfma(const u16* __restrict__ fullH, const u16* __restrict__ fullL,
               const u16* __restrict__ relH,  const u16* __restrict__ relL,
               const u16* __restrict__ WqTH,  const u16* __restrict__ WqTL,
               const u16* __restrict__ WkvTH, const u16* __restrict__ WkvTL,
               const u16* __restrict__ WrTH,  const u16* __restrict__ WrTL,
               const u16* __restrict__ atH,   const u16* __restrict__ atL,
               const u16* __restrict__ WoTH,  const u16* __restrict__ WoTL,
               const float* __restrict__ bias_c,
               float* __restrict__ qc, u16* __restrict__ kb16, u16* __restrict__ vb16,
               u16* __restrict__ rb16, float* __restrict__ outp, int base)
{
    __shared__ uint4 ldsbuf[2048];           // 32 KB: Ah | Al | Bh | Bl
    char* lds = (char*)ldsbuf;

    int bid = blockIdx.x;
    int mode, m0, n0, arow0, npass;
    const u16 *aH, *aL, *bH, *bL;
    if (base == 4) {
        // 16m x 8n grid; per-XCD rectangle 4m x 4n
        const int x = bid & 7, g = bid >> 3;             // g in [0,16)
        m0 = ((x >> 1) * 4 + (g >> 2)) * 128;
        n0 = ((x & 1) * 4 + (g & 3)) * 128;
        mode = 4; aH = atH; aL = atL; bH = WoTH; bL = WoTL; arow0 = m0; npass = 3;
    } else if (bid < 128) {
        // 16m x 8n grid; per-XCD rectangle 4m x 4n
        const int x = bid & 7, g = bid >> 3;             // g in [0,16)
        m0 = ((x >> 1) * 4 + (g >> 2)) * 128;
        n0 = ((x & 1) * 4 + (g & 3)) * 128;
        mode = 1; aH = fullH; aL = fullL; bH = WqTH; bL = WqTL;
        arow0 = (m0 >> 10) * cK + cM + (m0 & (cQ - 1)); npass = 2;
    } else if (bid < 640) {
        // 32m x 16n grid; per-XCD rectangle 8m x 8n
        const int local = bid - 128;
        const int x = local & 7, g = local >> 3;         // g in [0,64)
        m0 = ((x >> 1) * 8 + (g >> 3)) * 128;
        n0 = ((x & 1) * 8 + (g & 7)) * 128;
        mode = 2; aH = fullH; aL = fullL; bH = WkvTH; bL = WkvTL; arow0 = m0;
        npass = (n0 >= cU) ? 1 : 2;
    } else {
        // 32m x 8n grid; per-XCD rectangle 8m x 4n
        const int local = bid - 640;
        const int x = local & 7, g = local >> 3;         // g in [0,32)
        m0 = ((x >> 1) * 8 + (g >> 2)) * 128;
        n0 = ((x & 1) * 4 + (g & 3)) * 128;
        mode = 3; aH = relH; aL = relL; bH = WrTH; bL = WrTL; arow0 = m0; npass = 2;
    }

    const int t = threadIdx.x, w = t >> 6, lane = t & 63;

    const int rl = lane >> 2;
    const int cl = (lane & 3) ^ ((lane >> 3) & 3);  // XOR-swizzled chunk
    const u16* src;
    if (w == 0)      src = aH + (size_t)(arow0 + rl) * 1024 + cl * 8;
    else if (w == 1) src = aL + (size_t)(arow0 + rl) * 1024 + cl * 8;
    else if (w == 2) src = bH + (size_t)(n0 + rl) * 1024 + cl * 8;
    else             src = bL + (size_t)(n0 + rl) * 1024 + cl * 8;
    char* ldsw = lds + w * 8192;
    const bool doStage = (w == 0) || (w == 2) || (w == 1 && npass >= 2) || (w == 3 && npass >= 3);

    const int l31 = lane & 31, hk = lane >> 5;
    const int fsw = (l31 >> 1) & 3;
    const int koff[2] = { ((hk ^ fsw) << 4), (((2 + hk) ^ fsw) << 4) };
    const int mwb = (w >> 1) * 4096 + l31 * 64;
    const int nwb = (w & 1) * 4096 + l31 * 64;

    v16f acc[2][2];
    #pragma unroll
    for (int i = 0; i < 16; ++i) { acc[0][0][i] = 0.f; acc[0][1][i] = 0.f; acc[1][0][i] = 0.f; acc[1][1][i] = 0.f; }

    for (int kit = 0; kit < 32; ++kit) {
        __syncthreads();
        if (doStage) {
            #pragma unroll
            for (int g2 = 0; g2 < 8; ++g2)
                __builtin_amdgcn_global_load_lds((gp1)(src + (size_t)g2 * 16 * 1024),
                                                 (lp3)(ldsw + g2 * 1024), 16, 0, 0);
        }
        src += 32;
        __syncthreads();

        #pragma unroll
        for (int s = 0; s < 2; ++s) {
            const int ko = koff[s];
            const v8bf ah0 = *(const v8bf*)(lds + mwb + ko);
            const v8bf ah1 = *(const v8bf*)(lds + mwb + 2048 + ko);
            const v8bf bh0 = *(const v8bf*)(lds + 16384 + nwb + ko);
            const v8bf bh1 = *(const v8bf*)(lds + 16384 + nwb + 2048 + ko);
            acc[0][0] = MFMA32(ah0, bh0, acc[0][0]);
            acc[0][1] = MFMA32(ah0, bh1, acc[0][1]);
            acc[1][0] = MFMA32(ah1, bh0, acc[1][0]);
            acc[1][1] = MFMA32(ah1, bh1, acc[1][1]);
            if (npass >= 2) {
                const v8bf al0 = *(const v8bf*)(lds + 8192 + mwb + ko);
                const v8bf al1 = *(const v8bf*)(lds + 8192 + mwb + 2048 + ko);
                acc[0][0] = MFMA32(al0, bh0, acc[0][0]);
                acc[0][1] = MFMA32(al0, bh1, acc[0][1]);
                acc[1][0] = MFMA32(al1, bh0, acc[1][0]);
                acc[1][1] = MFMA32(al1, bh1, acc[1][1]);
            }
            if (npass >= 3) {
                const v8bf bl0 = *(const v8bf*)(lds + 24576 + nwb + ko);
                const v8bf bl1 = *(const v8bf*)(lds + 24576 + nwb + 2048 + ko);
                acc[0][0] = MFMA32(ah0, bl0, acc[0][0]);
                acc[0][1] = MFMA32(ah0, bl1, acc[0][1]);
                acc[1][0] = MFMA32(ah1, bl0, acc[1][0]);
                acc[1][1] = MFMA32(ah1, bl1, acc[1][1]);
            }
        }
    }

    #pragma unroll
    for (int mi = 0; mi < 2; ++mi)
    #pragma unroll
    for (int ni = 0; ni < 2; ++ni) {
        const int n = n0 + (w & 1) * 64 + ni * 32 + l31;
        #pragma unroll
        for (int e = 0; e < 16; ++e) {
            const int m = m0 + (w >> 1) * 64 + mi * 32 + (e & 3) + 8 * (e >> 2) + 4 * hk;
            const float v = acc[mi][ni][e];
            if (mode == 1) {
                const int b = m >> 10, q = m & (cQ - 1);
                const int h = n >> 6, d = n & 63;
                qc[(((size_t)(b * cH + h)) * cQ + q) * cD + d] = v + bias_c[n];
            } else if (mode == 2) {
                const int b = m >> 11, l = m & (cK - 1);
                const int nn = n & (cU - 1);
                const int h = nn >> 6, d = nn & 63;
                if (n >= cU)   // V fragment-linear
                    vb16[(size_t)(b * cH + h) * cK * cD + ((l >> 6) * 4096)
                         + (((l >> 4) & 3) * 1024) + (((l >> 3) & 1) * 512)
                         + d * 8 + (l & 7)] = f2bf(v);
                else           // K fragment-linear
                    kb16[(size_t)(b * cH + h) * cK * cD + ((l >> 6) * 4096)
                         + ((d >> 4) * 1024) + (((d >> 3) & 1) * 512)
                         + ((l & 63) * 8) + (d & 7)] = f2bf(v);
            } else if (mode == 3) {
                const int b = m >> 11, l = m & (cK - 1);
                const int h = n >> 6, d = n & 63;
                rb16[(size_t)(b * cH + h) * cRROWS * cD + ((l >> 5) * 2048)
                     + ((d >> 4) * 512) + (((d >> 3) & 1) * 256)
                     + ((l & 31) * 8) + (d & 7)] = f2bf(v);
            } else {
                outp[(size_t)m * cU + n] = v;
            }
        }
    }
}

// ---------------------------------------------------------------------------
// wvec: w_all[bh][win] = sum_d r[bh][win][d] * (bias_r - bias_c)[h][d]
// (reads R in fragment-linear order)
// ---------------------------------------------------------------------------
__global__ __launch_bounds__(256)
void wvec_kernel(const u16* __restrict__ rb16, const float* __restrict__ bias_c,
                 const float* __restrict__ bias_r, float* __restrict__ w_all)
{
    const int t = threadIdx.x, w = t >> 6, lane = t & 63;
    #pragma unroll 4
    for (int it = 0; it < 16; ++it) {
        const int row = blockIdx.x * 64 + it * 4 + w;    // 65536 rows
        const int bh = row >> 11, g = row & (cK - 1);
        const int h = bh & (cH - 1);
        const float d = bias_r[h * 64 + lane] - bias_c[h * 64 + lane];
        const size_t idx = (size_t)bh * cRROWS * cD + ((g >> 5) * 2048)
                         + ((lane >> 4) * 512) + (((lane >> 3) & 1) * 256)
                         + ((g & 31) * 8) + (lane & 7);
        float v = bf2f(rb16[idx]) * d;
        #pragma unroll
        for (int off = 1; off <= 32; off <<= 1)
            v += __shfl_xor(v, off);
        if (lane == 0) w_all[(size_t)bh * cWPAD + g] = v;
    }
}

// ---------------------------------------------------------------------------
// MFMA flash attention (unchanged from round 7): fragment-linear K/R staged
// via global_load_lds DMA, V coalesced register fragments, Q hi-only,
// 2 barriers/chunk, LDS 51.2 KB, split-K x2.
// ---------------------------------------------------------------------------
__global__ __launch_bounds__(256, 4)
void flash_mfma(const float* __restrict__ qcg, const u16* __restrict__ kbg,
                const u16* __restrict__ vbg, const u16* __restrict__ rbg,
                const float* __restrict__ w_all,
                float* __restrict__ oPart, float* __restrict__ lPart)
{
    __shared__ u16 KhL[4096];        // fragment-linear K chunk (8 KB)
    __shared__ u16 RhL[8192];        // fragment-linear R window (16 KB)
    __shared__ u16 SrelT[128][68];   // [window][q-row] bf16 (wv folded)
    __shared__ u16 Ph[64][68];       // [q-row][key] bf16
    __shared__ float lrow[2][64];

    const int bid = blockIdx.x;
    const int hb = bid & 31;
    const int inner = bid >> 5;
    const int qb = inner & 15;
    const int sp = inner >> 4;         // split 0/1
    const int h = hb >> 1, b = hb & 1;
    const int bh = b * cH + h;
    const int q0 = qb * 64;

    const u16* kgf = kbg + (size_t)bh * cK * cD;
    const u16* vgf = vbg + (size_t)bh * cK * cD;
    const u16* rgf = rbg + (size_t)bh * cRROWS * cD;
    const float* qg = qcg + (size_t)bh * cQ * cD;
    const float* wg = w_all + (size_t)bh * cWPAD;

    const int t = threadIdx.x, w = t >> 6, lane = t & 63;
    const int l31 = lane & 31, hk = lane >> 5;
    const int rloc0 = (w >> 1) * 32;
    const int c0 = (w & 1) * 32;
    const int wc0 = (w & 1) * 64 + l31;

    Frag qch[4];
    {
        const float* qrow = qg + (size_t)(q0 + rloc0 + l31) * cD;
        #pragma unroll
        for (int kc = 0; kc < 4; ++kc) {
            const int dh0 = kc * 16 + hk * 8;
            const float4 f0 = *(const float4*)(qrow + dh0);
            const float4 f1 = *(const float4*)(qrow + dh0 + 4);
            const float xs[8] = {f0.x, f0.y, f0.z, f0.w, f1.x, f1.y, f1.z, f1.w};
            #pragma unroll
            for (int j = 0; j < 8; ++j) qch[kc].s[j] = f2bf(xs[j]);
        }
    }

    v16f aO;
    float lpart[16];
    #pragma unroll
    for (int i = 0; i < 16; ++i) { aO[i] = 0.f; lpart[i] = 0.f; }

    const int nch = 17 + qb;
    int j0 = sp * 64;

    auto dma = [&](int jn, int relbn) {
        #pragma unroll
        for (int i = 0; i < 6; ++i) {
            const int id = w * 6 + i;
            if (id < 8) {
                const u16* s = kgf + (size_t)(jn >> 6) * 4096 + id * 512;
                __builtin_amdgcn_global_load_lds((gp1)(s + lane * 8),
                                                 (lp3)((char*)KhL + id * 1024), 16, 0, 0);
            } else {
                const int jj = id - 8;
                const u16* s = rgf + ((size_t)(relbn >> 5) + (jj >> 2)) * 2048 + (jj & 3) * 512;
                __builtin_amdgcn_global_load_lds((gp1)(s + lane * 8),
                                                 (lp3)((char*)RhL + jj * 1024), 16, 0, 0);
            }
        }
    };

    dma(j0, j0 - q0 + 960);
    __syncthreads();

    for (int c = sp; c < nch; c += 2) {
        const int relbase = j0 - q0 + 960;

        Frag vf[4];
        #pragma unroll
        for (int kc = 0; kc < 4; ++kc)
            vf[kc].q4 = *(const uint4*)(vgf + (size_t)(j0 >> 6) * 4096
                                        + kc * 1024 + hk * 512 + (c0 + l31) * 8);
        const float wv0 = wg[relbase + wc0];
        const float wv1 = wg[relbase + wc0 + 32];

        v16f actx;
        #pragma unroll
        for (int i = 0; i < 16; ++i) actx[i] = 0.f;
        #pragma unroll
        for (int kc = 0; kc < 4; ++kc) {
            Frag kf;
            kf.q4 = *(const uint4*)(KhL + kc * 1024 + hk * 512 + (c0 + l31) * 8);
            actx = MFMA32(qch[kc].v, kf.v, actx);
        }

        #pragma unroll
        for (int half = 0; half < 2; ++half) {
            v16f ar;
            #pragma unroll
            for (int i = 0; i < 16; ++i) ar[i] = 0.f;
            const int lg = (w & 1) * 2 + half;
            #pragma unroll
            for (int kc = 0; kc < 4; ++kc) {
                Frag rf;
                rf.q4 = *(const uint4*)(RhL + lg * 2048 + kc * 512 + hk * 256 + l31 * 8);
                ar = MFMA32(qch[kc].v, rf.v, ar);
            }
            const float wvh = half ? wv1 : wv0;
            const int wch = wc0 + half * 32;
            #pragma unroll
            for (int g = 0; g < 4; ++g) {
                const int rb_ = rloc0 + 8 * g + 4 * hk;
                u16 p[4];
                #pragma unroll
                for (int e = 0; e < 4; ++e) p[e] = f2bf(ar[4 * g + e] + wvh);
                *(uint2*)&SrelT[wch][rb_] = make_uint2(p[0] | ((u32)p[1] << 16),
                                                       p[2] | ((u32)p[3] << 16));
            }
        }
        __syncthreads();   // B: SrelT visible; KhL/RhL fully consumed

        const int jn = (c + 2 < nch) ? j0 + 128 : j0;
        dma(jn, jn - q0 + 960);

        const int jl = c0 + l31;
        const int limit = cM + q0 - j0;
        #pragma unroll
        for (int g = 0; g < 4; ++g)
        #pragma unroll
        for (int e = 0; e < 4; ++e) {
            const int reg  = 4 * g + e;
            const int rloc = rloc0 + e + 8 * g + 4 * hk;
            const int widx = jl - rloc + 63;            // [0,126]
            const float srel = bf2f(SrelT[widx][rloc]);
            const float s = (actx[reg] + srel) * 0.125f - 10.f;
            const float p = (jl > limit + rloc) ? 0.f : __expf(s);
            lpart[reg] += p;
            Ph[rloc][jl] = f2bf(p);
        }
        __syncthreads();   // C: Ph visible; DMA drained

        #pragma unroll
        for (int kc = 0; kc < 4; ++kc) {
            const int kb0 = kc * 16 + hk * 8;
            Frag pf;
            pf.d2[0] = *(const uint2*)&Ph[rloc0 + l31][kb0];
            pf.d2[1] = *(const uint2*)&Ph[rloc0 + l31][kb0 + 4];
            aO = MFMA32(pf.v, vf[kc].v, aO);
        }
        j0 += 128;
    }

    #pragma unroll
    for (int off = 1; off <= 16; off <<= 1)
        #pragma unroll
        for (int i = 0; i < 16; ++i) lpart[i] += __shfl_xor(lpart[i], off);
    if (l31 == 0) {
        #pragma unroll
        for (int g = 0; g < 4; ++g)
        #pragma unroll
        for (int e = 0; e < 4; ++e)
            lrow[w & 1][rloc0 + e + 8 * g + 4 * hk] = lpart[4 * g + e];
    }
    __syncthreads();

    float* ob = oPart + (size_t)sp * ((size_t)cB * cQ * cU);
    #pragma unroll
    for (int g = 0; g < 4; ++g)
    #pragma unroll
    for (int e = 0; e < 4; ++e) {
        const int reg  = 4 * g + e;
        const int rloc = rloc0 + e + 8 * g + 4 * hk;
        ob[((size_t)(b * cQ + q0 + rloc)) * cU + h * 64 + c0 + l31] = aO[reg];
    }
    if (t < 64)
        lPart[(size_t)sp * (cB * cH * cQ) + (size_t)bh * cQ + q0 + t] = lrow[0][t] + lrow[1][t];
}

// ---------------------------------------------------------------------------
// combine: o = (o0+o1)/(l0+l1), write bf16 hi/lo for the out-GEMM.
// (oPart must stay fp32: unnormalized o ~ 200 -> bf16 rounding would inject
//  ~1.3e-3 output error, over budget.)
// ---------------------------------------------------------------------------
__global__ __launch_bounds__(256)
void combine(const float* __restrict__ oPart, const float* __restrict__ lPart,
             u16* __restrict__ atH, u16* __restrict__ atL)
{
    const int idx = blockIdx.x * 256 + threadIdx.x;
    const size_t base = (size_t)idx * 4;
    const int b = (int)(base >> 20);
    const int rem = (int)(base & ((1u << 20) - 1));
    const int q = rem >> 10;
    const int u = rem & 1023;
    const int h = u >> 6;
    const float4 o0 = *(const float4*)(oPart + base);
    const float4 o1 = *(const float4*)(oPart + (size_t)cB * cQ * cU + base);
    const int li = (b * cH + h) * cQ + q;
    const float l = lPart[li] + lPart[cB * cH * cQ + li];
    const float inv = 1.f / l;
    const float vals[4] = {(o0.x + o1.x) * inv, (o0.y + o1.y) * inv,
                           (o0.z + o1.z) * inv, (o0.w + o1.w) * inv};
    u16 hi[4], lo[4];
    #pragma unroll
    for (int j = 0; j < 4; ++j) {
        hi[j] = f2bf(vals[j]);
        lo[j] = f2bf(vals[j] - bf2f(hi[j]));
    }
    uint2 ph, pl;
    ph.x = hi[0] | ((u32)hi[1] << 16); ph.y = hi[2] | ((u32)hi[3] << 16);
    pl.x = lo[0] | ((u32)lo[1] << 16); pl.y = lo[2] | ((u32)lo[3] << 16);
    *(uint2*)(atH + base) = ph;
    *(uint2*)(atL + base) = pl;
}

// ---------------------------------------------------------------------------
extern "C" void kernel_launch(void* const* d_in, const int* in_sizes, int n_in,
                              void* d_out, int out_size, void* d_ws, size_t ws_size,
                              hipStream_t stream)
{
    const float* inputs    = (const float*)d_in[0];
    const float* relatives = (const float*)d_in[1];
    const float* memories  = (const float*)d_in[2];
    const float* bias_c    = (const float*)d_in[3];
    const float* bias_r    = (const float*)d_in[4];
    const float* Wq        = (const float*)d_in[5];
    const float* Wkv       = (const float*)d_in[6];
    const float* Wr        = (const float*)d_in[7];
    const float* Wo        = (const float*)d_in[8];
    float* out = (float*)d_out;

    char* p = (char*)d_ws;
    auto alloc = [&](size_t bytes) { char* r = p; p += bytes; return r; };
    u16* fullH = (u16*)alloc(8u << 20);
    u16* fullL = (u16*)alloc(8u << 20);
    u16* relH  = (u16*)alloc(8u << 20);   // oPart aliases relH+relL after proj
    u16* relL  = (u16*)alloc(8u << 20);
    u16* WqTH  = (u16*)alloc(2u << 20);
    u16* WqTL  = (u16*)alloc(2u << 20);
    u16* WkvTH = (u16*)alloc(4u << 20);
    u16* WkvTL = (u16*)alloc(4u << 20);
    u16* WrTH  = (u16*)alloc(2u << 20);
    u16* WrTL  = (u16*)alloc(2u << 20);
    u16* WoTH  = (u16*)alloc(2u << 20);
    u16* WoTL  = (u16*)alloc(2u << 20);
    float* qc  = (float*)alloc(8u << 20);
    u16* kb16  = (u16*)alloc(8u << 20);
    u16* vb16  = (u16*)alloc(8u << 20);
    u16* rb16  = (u16*)alloc(9u << 20);   // 32 bh x 2112 rows x 64 (fragment-linear)
    float* w_all = (float*)alloc(32u * cWPAD * 4u);
    float* lPart = (float*)alloc(2u * cB * cH * cQ * 4u);
    u16* atH   = (u16*)alloc(4u << 20);
    u16* atL   = (u16*)alloc(4u << 20);
    float* oPart = (float*)relH;          // 16 MB, reuses rel planes

    convert_acts<<<8192, 256, 0, stream>>>(inputs, memories, relatives,
                                           fullH, fullL, relH, relL);
    convert_wT<<<1280, 256, 0, stream>>>(Wq, Wkv, Wr, Wo,
                                         WqTH, WqTL, WkvTH, WkvTL,
                                         WrTH, WrTL, WoTH, WoTL);
    gemm_mfma<<<896, 256, 0, stream>>>(fullH, fullL, relH, relL,
                                       WqTH, WqTL, WkvTH, WkvTL, WrTH, WrTL,
                                       atH, atL, WoTH, WoTL, bias_c,
                                       qc, kb16, vb16, rb16, out, 0);
    wvec_kernel<<<1024, 256, 0, stream>>>(rb16, bias_c, bias_r, w_all);
    flash_mfma<<<1024, 256, 0, stream>>>(qc, kb16, vb16, rb16, w_all, oPart, lPart);
    combine<<<2048, 256, 0, stream>>>(oPart, lPart, atH, atL);
    gemm_mfma<<<128, 256, 0, stream>>>(fullH, fullL, relH, relL,
                                       WqTH, WqTL, WkvTH, WkvTL, WrTH, WrTL,
                                       atH, atL, WoTH, WoTL, bias_c,
                                       qc, kb16, vb16, rb16, out, 4);
}